// Round 2
// baseline (5118.480 us; speedup 1.0000x reference)
//
#include <hip/hip_runtime.h>
#include <math.h>

#define N_NODES 100000
#define N_EDGES 800000
#define NODE_IN 32
#define EDGE_DIM 84
#define HIDDEN 24
#define HEAD_HIDDEN 20
#define CAT_DIM 132            // 2*HIDDEN + EDGE_DIM
#define LN_EPS 1e-5f
#define TILE_E 256             // edges per block = threads per block
#define CB 12                  // k-chunk width (132 = 11*12, 84 = 7*12)
#define CBP 13                 // padded row stride (gcd(13,32)=1 -> conflict-free)
#define NCH 11                 // 132/12

__device__ __forceinline__ float gelu_exact(float x) {
    return 0.5f * x * (1.0f + erff(x * 0.70710678118654752f));
}

// ---------------- node input projection + intrinsic head ----------------
__global__ void k_node_in(const float* __restrict__ x,
                          const float* __restrict__ node_w, const float* __restrict__ node_b,
                          const float* __restrict__ ih_w1, const float* __restrict__ ih_b1,
                          const float* __restrict__ ih_w2, const float* __restrict__ ih_b2,
                          float* __restrict__ h, float* __restrict__ intr) {
    int n = blockIdx.x * blockDim.x + threadIdx.x;
    if (n >= N_NODES) return;
    float xv[NODE_IN];
    const float4* xp = (const float4*)(x + (size_t)n * NODE_IN);
#pragma unroll
    for (int i = 0; i < NODE_IN / 4; i++) {
        float4 v = xp[i];
        xv[4*i+0] = v.x; xv[4*i+1] = v.y; xv[4*i+2] = v.z; xv[4*i+3] = v.w;
    }
    float hv[HIDDEN];
#pragma unroll
    for (int j = 0; j < HIDDEN; j++) hv[j] = node_b[j];
    for (int k = 0; k < NODE_IN; k++) {
        float xk = xv[k];
#pragma unroll
        for (int j = 0; j < HIDDEN; j++) hv[j] = fmaf(xk, node_w[k * HIDDEN + j], hv[j]);
    }
    float* hp = h + (size_t)n * HIDDEN;
#pragma unroll
    for (int j = 0; j < HIDDEN; j++) hp[j] = hv[j];
    float acc = ih_b2[0];
    for (int j = 0; j < HEAD_HIDDEN; j++) {
        float t = ih_b1[j];
#pragma unroll
        for (int k = 0; k < HIDDEN; k++) t = fmaf(hv[k], ih_w1[k * HEAD_HIDDEN + j], t);
        acc = fmaf(gelu_exact(t), ih_w2[j], acc);
    }
    intr[n] = acc;
}

// ---------------- in-degree counts ----------------
__global__ void k_counts(const int* __restrict__ ei, int* __restrict__ cnt) {
    int e = blockIdx.x * blockDim.x + threadIdx.x;
    if (e >= N_EDGES) return;
    atomicAdd(&cnt[ei[N_EDGES + e]], 1);
}

// Stage one 12-wide k-chunk of cat = [h[src], h[dst], e] for 256 edges into LDS.
// buf rows are padded to CBP=13. Chunk regions align exactly: cc 0-1 src,
// 2-3 dst, 4-10 e.
__device__ __forceinline__ void stage_chunk(int cc, float* __restrict__ buf,
                                            const float* __restrict__ h,
                                            const float* __restrict__ e_in,
                                            const int* __restrict__ s_src,
                                            const int* __restrict__ s_dst,
                                            int e0, int tid) {
    int k0 = cc * CB;
#pragma unroll
    for (int i = 0; i < CB; i++) {
        int idx = tid + 256 * i;          // 0..3071
        int e = idx / CB;
        int k = idx - e * CB;
        int kg = k0 + k;
        float v;
        if (kg < HIDDEN)
            v = h[(size_t)s_src[e] * HIDDEN + kg];
        else if (kg < 2 * HIDDEN)
            v = h[(size_t)s_dst[e] * HIDDEN + (kg - HIDDEN)];
        else
            v = e_in[(size_t)(e0 + e) * EDGE_DIM + (kg - 2 * HIDDEN)];
        buf[e * CBP + k] = v;
    }
}

// ---------------- phi_e + residual + LayerNorm, edge-per-lane ----------------
__global__ __launch_bounds__(256, 2)
void k_edge_e(const float* __restrict__ h, const float* __restrict__ e_in,
              const int* __restrict__ ei,
              const float* __restrict__ w1, const float* __restrict__ b1,
              const float* __restrict__ w2, const float* __restrict__ b2,
              const float* __restrict__ g, const float* __restrict__ bb,
              float* __restrict__ e_out) {
    __shared__ float s_buf[2][TILE_E * CBP];
    __shared__ int s_src[TILE_E], s_dst[TILE_E];

    const int tid = threadIdx.x;
    const int e0 = blockIdx.x * TILE_E;
    s_src[tid] = ei[e0 + tid];
    s_dst[tid] = ei[N_EDGES + e0 + tid];
    __syncthreads();

    stage_chunk(0, s_buf[0], h, e_in, s_src, s_dst, e0, tid);

    float acc[EDGE_DIM];
#pragma unroll
    for (int j = 0; j < EDGE_DIM; j++) acc[j] = 0.f;

    // GEMM1: acc = cat @ w1   (K=132 in 11 chunks, weights via scalar loads)
#pragma unroll 1
    for (int c = 0; c < NCH; c++) {
        __syncthreads();   // chunk c staged; buffer (c+1)&1 free
        if (c + 1 < NCH)
            stage_chunk(c + 1, s_buf[(c + 1) & 1], h, e_in, s_src, s_dst, e0, tid);
        const float* __restrict__ wrow = w1 + (size_t)c * CB * EDGE_DIM;
        const float* __restrict__ row = &s_buf[c & 1][tid * CBP];
#pragma unroll
        for (int kk = 0; kk < CB; kk++) {
            float cv = row[kk];
#pragma unroll
            for (int j = 0; j < EDGE_DIM; j++)
                acc[j] = fmaf(cv, wrow[kk * EDGE_DIM + j], acc[j]);
        }
    }

    // t = gelu(acc + b1)  (keep in regs)
    float t[EDGE_DIM];
#pragma unroll
    for (int j = 0; j < EDGE_DIM; j++) t[j] = gelu_exact(acc[j] + b1[j]);

    // GEMM2: acc2 = t @ w2, K=84 in 7 chunks of 12. Each lane bounces its own
    // 12 t-values through a private LDS strip so the k-loop can index them at
    // runtime (keeps code rolled). Rows are per-lane private -> no barrier.
    float acc2[EDGE_DIM];
#pragma unroll
    for (int j = 0; j < EDGE_DIM; j++) acc2[j] = 0.f;
    float* __restrict__ st = &s_buf[0][tid * CBP];
#pragma unroll
    for (int cc = 0; cc < 7; cc++) {
#pragma unroll
        for (int kk = 0; kk < CB; kk++) st[kk] = t[cc * CB + kk];
        const float* __restrict__ wrow = w2 + (size_t)cc * CB * EDGE_DIM;
#pragma unroll 1
        for (int kk = 0; kk < CB; kk++) {
            float cv = st[kk];
#pragma unroll
            for (int j = 0; j < EDGE_DIM; j++)
                acc2[j] = fmaf(cv, wrow[kk * EDGE_DIM + j], acc2[j]);
        }
    }

    // residual: r = e_old + acc2 + b2  (re-read own row, contiguous float4s)
    const float* __restrict__ erow = e_in + (size_t)(e0 + tid) * EDGE_DIM;
#pragma unroll
    for (int j = 0; j < EDGE_DIM; j++) acc2[j] += erow[j] + b2[j];

    // LayerNorm over 84 (per-lane, serial reduce in regs)
    float s = 0.f, sq = 0.f;
#pragma unroll
    for (int j = 0; j < EDGE_DIM; j++) { s += acc2[j]; sq = fmaf(acc2[j], acc2[j], sq); }
    float mean = s * (1.f / EDGE_DIM);
    float var = sq * (1.f / EDGE_DIM) - mean * mean;
    float rstd = rsqrtf(var + LN_EPS);
    float* __restrict__ orow = e_out + (size_t)(e0 + tid) * EDGE_DIM;
#pragma unroll
    for (int j = 0; j < EDGE_DIM; j++)
        orow[j] = (acc2[j] - mean) * rstd * g[j] + bb[j];
}

// ---------------- phi_v + scatter-add, edge-per-lane ----------------
__global__ __launch_bounds__(256, 4)
void k_edge_v(const float* __restrict__ h, const float* __restrict__ e_in,
              const int* __restrict__ ei,
              const float* __restrict__ v1, const float* __restrict__ vb1,
              const float* __restrict__ v2, const float* __restrict__ vb2,
              float* __restrict__ agg) {
    __shared__ float s_buf[2][TILE_E * CBP];   // also reused as s_m[256][24]
    __shared__ int s_src[TILE_E], s_dst[TILE_E];

    const int tid = threadIdx.x;
    const int e0 = blockIdx.x * TILE_E;
    s_src[tid] = ei[e0 + tid];
    s_dst[tid] = ei[N_EDGES + e0 + tid];
    __syncthreads();

    stage_chunk(0, s_buf[0], h, e_in, s_src, s_dst, e0, tid);

    float acc[HIDDEN];
#pragma unroll
    for (int j = 0; j < HIDDEN; j++) acc[j] = 0.f;

#pragma unroll 1
    for (int c = 0; c < NCH; c++) {
        __syncthreads();
        if (c + 1 < NCH)
            stage_chunk(c + 1, s_buf[(c + 1) & 1], h, e_in, s_src, s_dst, e0, tid);
        const float* __restrict__ wrow = v1 + (size_t)c * CB * HIDDEN;
        const float* __restrict__ row = &s_buf[c & 1][tid * CBP];
#pragma unroll
        for (int kk = 0; kk < CB; kk++) {
            float cv = row[kk];
#pragma unroll
            for (int j = 0; j < HIDDEN; j++)
                acc[j] = fmaf(cv, wrow[kk * HIDDEN + j], acc[j]);
        }
    }

    float t[HIDDEN];
#pragma unroll
    for (int j = 0; j < HIDDEN; j++) t[j] = gelu_exact(acc[j] + vb1[j]);

    float acc2[HIDDEN];
#pragma unroll
    for (int j = 0; j < HIDDEN; j++) acc2[j] = vb2[j];
#pragma unroll
    for (int k = 0; k < HIDDEN; k++) {     // fully unrolled: t reg-indexable
        float cv = t[k];
#pragma unroll
        for (int j = 0; j < HIDDEN; j++)
            acc2[j] = fmaf(cv, v2[k * HIDDEN + j], acc2[j]);
    }

    // stage m into LDS (flat [256][24] over s_buf storage), then coalesced atomics
    __syncthreads();   // everyone done reading staged cat
    float* __restrict__ s_m = &s_buf[0][0];
#pragma unroll
    for (int j = 0; j < HIDDEN; j++) s_m[tid * HIDDEN + j] = acc2[j];
    __syncthreads();
#pragma unroll
    for (int i = 0; i < HIDDEN; i++) {
        int idx = tid + 256 * i;           // 0..6143
        int e = idx / HIDDEN;
        int j = idx - e * HIDDEN;
        atomicAdd(&agg[(size_t)s_dst[e] * HIDDEN + j], s_m[idx]);
    }
}

// ---------------- node update: h = LN(h + agg/counts) ----------------
__global__ void k_node_up(float* __restrict__ h, const float* __restrict__ agg,
                          const int* __restrict__ cnt,
                          const float* __restrict__ g, const float* __restrict__ b) {
    int n = blockIdx.x * blockDim.x + threadIdx.x;
    if (n >= N_NODES) return;
    int c = cnt[n]; if (c < 1) c = 1;
    float inv = 1.0f / (float)c;
    float v[HIDDEN];
    float s = 0.f;
#pragma unroll
    for (int j = 0; j < HIDDEN; j++) {
        v[j] = h[(size_t)n * HIDDEN + j] + agg[(size_t)n * HIDDEN + j] * inv;
        s += v[j];
    }
    float mean = s * (1.f / HIDDEN);
    float sq = 0.f;
#pragma unroll
    for (int j = 0; j < HIDDEN; j++) { float d = v[j] - mean; sq = fmaf(d, d, sq); }
    float rstd = rsqrtf(sq * (1.f / HIDDEN) + LN_EPS);
#pragma unroll
    for (int j = 0; j < HIDDEN; j++)
        h[(size_t)n * HIDDEN + j] = (v[j] - mean) * rstd * g[j] + b[j];
}

// ---------------- final: out = mu + intrinsic + context(h) ----------------
__global__ void k_final(const float* __restrict__ h, const float* __restrict__ intr,
                        const float* __restrict__ ch_w1, const float* __restrict__ ch_b1,
                        const float* __restrict__ ch_w2, const float* __restrict__ ch_b2,
                        const float* __restrict__ mu, float* __restrict__ out) {
    int n = blockIdx.x * blockDim.x + threadIdx.x;
    if (n >= N_NODES) return;
    float hv[HIDDEN];
#pragma unroll
    for (int j = 0; j < HIDDEN; j++) hv[j] = h[(size_t)n * HIDDEN + j];
    float acc = ch_b2[0];
    for (int j = 0; j < HEAD_HIDDEN; j++) {
        float t = ch_b1[j];
#pragma unroll
        for (int k = 0; k < HIDDEN; k++) t = fmaf(hv[k], ch_w1[k * HEAD_HIDDEN + j], t);
        acc = fmaf(gelu_exact(t), ch_w2[j], acc);
    }
    out[n] = mu[0] + intr[n] + acc;
}

extern "C" void kernel_launch(void* const* d_in, const int* in_sizes, int n_in,
                              void* d_out, int out_size, void* d_ws, size_t ws_size,
                              hipStream_t stream) {
    const float* x        = (const float*)d_in[0];
    const float* edge_attr= (const float*)d_in[1];
    const float* node_w   = (const float*)d_in[2];
    const float* node_b   = (const float*)d_in[3];
    const float* ih_w1    = (const float*)d_in[4];
    const float* ih_b1    = (const float*)d_in[5];
    const float* ih_w2    = (const float*)d_in[6];
    const float* ih_b2    = (const float*)d_in[7];
    const float* pe_w1    = (const float*)d_in[8];
    const float* pe_b1    = (const float*)d_in[9];
    const float* pe_w2    = (const float*)d_in[10];
    const float* pe_b2    = (const float*)d_in[11];
    const float* pv_w1    = (const float*)d_in[12];
    const float* pv_b1    = (const float*)d_in[13];
    const float* pv_w2    = (const float*)d_in[14];
    const float* pv_b2    = (const float*)d_in[15];
    const float* ne_g     = (const float*)d_in[16];
    const float* ne_b     = (const float*)d_in[17];
    const float* nv_g     = (const float*)d_in[18];
    const float* nv_b     = (const float*)d_in[19];
    const float* ch_w1    = (const float*)d_in[20];
    const float* ch_b1    = (const float*)d_in[21];
    const float* ch_w2    = (const float*)d_in[22];
    const float* ch_b2    = (const float*)d_in[23];
    const float* mu       = (const float*)d_in[24];
    const int*   ei       = (const int*)d_in[25];

    char* ws = (char*)d_ws;
    float* h    = (float*)ws; ws += (size_t)N_NODES * HIDDEN * 4;
    float* agg  = (float*)ws; ws += (size_t)N_NODES * HIDDEN * 4;
    float* intr = (float*)ws; ws += (size_t)N_NODES * 4;
    int*   cnt  = (int*)ws;   ws += (size_t)N_NODES * 4;
    float* e_ws = (float*)ws; ws += (size_t)N_EDGES * EDGE_DIM * 4;

    hipMemsetAsync(cnt, 0, (size_t)N_NODES * 4, stream);
    k_counts<<<(N_EDGES + 255) / 256, 256, 0, stream>>>(ei, cnt);
    k_node_in<<<(N_NODES + 255) / 256, 256, 0, stream>>>(
        x, node_w, node_b, ih_w1, ih_b1, ih_w2, ih_b2, h, intr);

    const int eb = N_EDGES / TILE_E;  // 3125, exact
    for (int L = 0; L < 2; L++) {
        const float* ein = (L == 0) ? edge_attr : e_ws;  // layer1 updates e_ws in place
        k_edge_e<<<eb, 256, 0, stream>>>(
            h, ein, ei,
            pe_w1 + (size_t)L * CAT_DIM * EDGE_DIM, pe_b1 + (size_t)L * EDGE_DIM,
            pe_w2 + (size_t)L * EDGE_DIM * EDGE_DIM, pe_b2 + (size_t)L * EDGE_DIM,
            ne_g + (size_t)L * EDGE_DIM, ne_b + (size_t)L * EDGE_DIM, e_ws);
        hipMemsetAsync(agg, 0, (size_t)N_NODES * HIDDEN * 4, stream);
        k_edge_v<<<eb, 256, 0, stream>>>(
            h, e_ws, ei,
            pv_w1 + (size_t)L * CAT_DIM * HIDDEN, pv_b1 + (size_t)L * HIDDEN,
            pv_w2 + (size_t)L * HIDDEN * HIDDEN, pv_b2 + (size_t)L * HIDDEN, agg);
        k_node_up<<<(N_NODES + 255) / 256, 256, 0, stream>>>(
            h, agg, cnt, nv_g + (size_t)L * HIDDEN, nv_b + (size_t)L * HIDDEN);
    }
    k_final<<<(N_NODES + 255) / 256, 256, 0, stream>>>(
        h, intr, ch_w1, ch_b1, ch_w2, ch_b2, mu, (float*)d_out);
}

// Round 3
// 1159.209 us; speedup vs baseline: 4.4155x; 4.4155x over previous
//
#include <hip/hip_runtime.h>
#include <math.h>

#define N_NODES 100000
#define N_EDGES 800000
#define NODE_IN 32
#define EDGE_DIM 84
#define HIDDEN 24
#define HEAD_HIDDEN 20
#define CAT_DIM 132
#define LN_EPS 1e-5f

typedef __attribute__((ext_vector_type(8))) short short8;
typedef __attribute__((ext_vector_type(4))) float f32x4;
typedef unsigned int uint;
typedef unsigned short ushort;

__device__ __forceinline__ float gelu_exact(float x) {
    return 0.5f * x * (1.0f + erff(x * 0.70710678118654752f));
}
__device__ __forceinline__ ushort f2bf(float f) {
    union { float f; uint u; } c; c.f = f;
    uint u = c.u;
    return (ushort)((u + 0x7fffu + ((u >> 16) & 1u)) >> 16);
}
__device__ __forceinline__ float bf2f(ushort s) {
    union { uint u; float f; } c; c.u = ((uint)s) << 16; return c.f;
}

// ---------------- weight pre-pack to MFMA-fragment-major bf16 ----------------
// frag layout: element (lane, j) = W[kt*32 + (lane>>4)*8 + j][nt*16 + (lane&15)]
// regions (in frags of 512 bf16): pe_w1 2L*30 | pe_w2 2L*18 | pv_w1 2L*10 | pv_w2 2L*2
__global__ void k_prep_w(const float* __restrict__ pe_w1, const float* __restrict__ pe_w2,
                         const float* __restrict__ pv_w1, const float* __restrict__ pv_w2,
                         ushort* __restrict__ wp) {
    int idx = blockIdx.x * 256 + threadIdx.x;        // < 61440
    int j = idx & 7;
    int lane = (idx >> 3) & 63;
    int frag = idx >> 9;                             // 0..119
    int kq = (lane >> 4) * 8 + j;
    int n15 = lane & 15;
    float v = 0.f;
    if (frag < 60) {                                 // pe_w1: [L][5kt][6nt]
        int l = frag / 30, f = frag % 30;
        int kt = f / 6, nt = f % 6;
        int k = kt * 32 + kq, n = nt * 16 + n15;
        if (k < CAT_DIM && n < EDGE_DIM) v = pe_w1[(l * CAT_DIM + k) * EDGE_DIM + n];
    } else if (frag < 96) {                          // pe_w2: [L][3kt][6nt]
        int f2 = frag - 60; int l = f2 / 18, f = f2 % 18;
        int kt = f / 6, nt = f % 6;
        int k = kt * 32 + kq, n = nt * 16 + n15;
        if (k < EDGE_DIM && n < EDGE_DIM) v = pe_w2[(l * EDGE_DIM + k) * EDGE_DIM + n];
    } else if (frag < 116) {                         // pv_w1: [L][5kt][2nt]
        int f2 = frag - 96; int l = f2 / 10, f = f2 % 10;
        int kt = f / 2, nt = f % 2;
        int k = kt * 32 + kq, n = nt * 16 + n15;
        if (k < CAT_DIM && n < HIDDEN) v = pv_w1[(l * CAT_DIM + k) * HIDDEN + n];
    } else {                                         // pv_w2: [L][1kt][2nt]
        int f2 = frag - 116; int l = f2 / 2, nt = f2 % 2;
        int k = kq, n = nt * 16 + n15;
        if (k < HIDDEN && n < HIDDEN) v = pv_w2[(l * HIDDEN + k) * HIDDEN + n];
    }
    wp[idx] = f2bf(v);
}

// ---------------- node input projection + intrinsic head ----------------
__global__ void k_node_in(const float* __restrict__ x,
                          const float* __restrict__ node_w, const float* __restrict__ node_b,
                          const float* __restrict__ ih_w1, const float* __restrict__ ih_b1,
                          const float* __restrict__ ih_w2, const float* __restrict__ ih_b2,
                          float* __restrict__ h, ushort* __restrict__ h_bf,
                          float* __restrict__ intr) {
    int n = blockIdx.x * blockDim.x + threadIdx.x;
    if (n >= N_NODES) return;
    float xv[NODE_IN];
    const float4* xp = (const float4*)(x + (size_t)n * NODE_IN);
#pragma unroll
    for (int i = 0; i < NODE_IN / 4; i++) {
        float4 v = xp[i];
        xv[4*i+0] = v.x; xv[4*i+1] = v.y; xv[4*i+2] = v.z; xv[4*i+3] = v.w;
    }
    float hv[HIDDEN];
#pragma unroll
    for (int j = 0; j < HIDDEN; j++) hv[j] = node_b[j];
    for (int k = 0; k < NODE_IN; k++) {
        float xk = xv[k];
#pragma unroll
        for (int j = 0; j < HIDDEN; j++) hv[j] = fmaf(xk, node_w[k * HIDDEN + j], hv[j]);
    }
#pragma unroll
    for (int j = 0; j < HIDDEN; j++) {
        h[(size_t)n * HIDDEN + j] = hv[j];
        h_bf[(size_t)n * HIDDEN + j] = f2bf(hv[j]);
    }
    float acc = ih_b2[0];
    for (int j = 0; j < HEAD_HIDDEN; j++) {
        float t = ih_b1[j];
#pragma unroll
        for (int k = 0; k < HIDDEN; k++) t = fmaf(hv[k], ih_w1[k * HEAD_HIDDEN + j], t);
        acc = fmaf(gelu_exact(t), ih_w2[j], acc);
    }
    intr[n] = acc;
}

__global__ void k_counts(const int* __restrict__ ei, int* __restrict__ cnt) {
    int e = blockIdx.x * blockDim.x + threadIdx.x;
    if (e >= N_EDGES) return;
    atomicAdd(&cnt[ei[N_EDGES + e]], 1);
}

// ---------------- phi_e MFMA kernel: 128 edges/block, 4 waves ----------------
// A (cat, bf16) in LDS: 128 rows x 160 cols (pad->168 bf16 = 84 dwords pitch)
// GEMM1: [128x160]@[160x96] -> gelu -> t LDS [128x96] (pitch 104 bf16)
// GEMM2: [128x96]@[96x96] -> +b2 +e_old -> LN -> bf16 back into A e-cols -> store
__global__ __launch_bounds__(256, 2)
void k_edge_e(const ushort* __restrict__ h_bf,
              const float* __restrict__ e_in_f32,   // layer0 edge_attr, else null
              ushort* __restrict__ e_bf,            // in (L>0) and out
              const int* __restrict__ ei,
              const ushort* __restrict__ w1f, const ushort* __restrict__ w2f,
              const float* __restrict__ b1, const float* __restrict__ b2,
              const float* __restrict__ g, const float* __restrict__ bb) {
    __shared__ __align__(16) uint sA32[128 * 84];
    __shared__ __align__(16) ushort sT[128 * 104];
    __shared__ int s_idx[256];

    const int tid = threadIdx.x;
    const int e0 = blockIdx.x * 128;
    s_idx[tid] = ei[(size_t)(tid >> 7) * N_EDGES + e0 + (tid & 127)];
    __syncthreads();

    // ---- assemble A: 2 threads per edge row ----
    {
        int e = tid >> 1, hf = tid & 1;
        int src = s_idx[e], dst = s_idx[128 + e];
        const uint* hb = (const uint*)h_bf;
        uint* row = sA32 + e * 84;
#pragma unroll
        for (int i = 0; i < 6; i++) row[hf * 6 + i] = hb[src * 12 + hf * 6 + i];
#pragma unroll
        for (int i = 0; i < 6; i++) row[12 + hf * 6 + i] = hb[dst * 12 + hf * 6 + i];
        if (e_in_f32) {
            const float* er = e_in_f32 + (size_t)(e0 + e) * 84;
#pragma unroll
            for (int i = 0; i < 21; i++) {
                int jd = hf * 21 + i;
                uint lo = f2bf(er[2 * jd]), hi = f2bf(er[2 * jd + 1]);
                row[24 + jd] = lo | (hi << 16);
            }
        } else {
            const uint* er = (const uint*)e_bf + (size_t)(e0 + e) * 42;
#pragma unroll
            for (int i = 0; i < 21; i++) { int jd = hf * 21 + i; row[24 + jd] = er[jd]; }
        }
#pragma unroll
        for (int i = 0; i < 7; i++) row[66 + hf * 7 + i] = 0u;
    }

    const int lane = tid & 63, wave = tid >> 6;
    const int quad = lane >> 4, l15 = lane & 15;
    float b1v[6], b2v[6], gv[6], bbv[6];
#pragma unroll
    for (int nt = 0; nt < 6; nt++) {
        int col = nt * 16 + l15;
        bool ok = col < EDGE_DIM;
        b1v[nt] = ok ? b1[col] : 0.f;
        b2v[nt] = ok ? b2[col] : 0.f;
        gv[nt]  = ok ? g[col]  : 0.f;
        bbv[nt] = ok ? bb[col] : 0.f;
    }
    __syncthreads();

    const ushort* sAu = (const ushort*)sA32;
    const int r0 = wave * 32 + l15;

    f32x4 acc[2][6];
#pragma unroll
    for (int mt = 0; mt < 2; mt++)
#pragma unroll
        for (int nt = 0; nt < 6; nt++) acc[mt][nt] = (f32x4)0.f;

#pragma unroll
    for (int kt = 0; kt < 5; kt++) {
        short8 a0 = *(const short8*)(sAu + (size_t)r0 * 168 + kt * 32 + quad * 8);
        short8 a1 = *(const short8*)(sAu + (size_t)(r0 + 16) * 168 + kt * 32 + quad * 8);
        const short8* bp = (const short8*)w1f + kt * 6 * 64 + lane;
#pragma unroll
        for (int nt = 0; nt < 6; nt++) {
            short8 b = bp[nt * 64];
            acc[0][nt] = __builtin_amdgcn_mfma_f32_16x16x32_bf16(a0, b, acc[0][nt], 0, 0, 0);
            acc[1][nt] = __builtin_amdgcn_mfma_f32_16x16x32_bf16(a1, b, acc[1][nt], 0, 0, 0);
        }
    }

    // t = gelu(acc + b1) -> sT (cols>=84 are exactly 0 via zero-pad weights+bias)
#pragma unroll
    for (int mt = 0; mt < 2; mt++)
#pragma unroll
        for (int nt = 0; nt < 6; nt++)
#pragma unroll
            for (int r = 0; r < 4; r++) {
                int row = wave * 32 + mt * 16 + quad * 4 + r;
                sT[row * 104 + nt * 16 + l15] = f2bf(gelu_exact(acc[mt][nt][r] + b1v[nt]));
            }
    __syncthreads();

    f32x4 acc2[2][6];
#pragma unroll
    for (int mt = 0; mt < 2; mt++)
#pragma unroll
        for (int nt = 0; nt < 6; nt++) acc2[mt][nt] = (f32x4)0.f;

#pragma unroll
    for (int kt = 0; kt < 3; kt++) {
        short8 a0 = *(const short8*)(sT + (size_t)r0 * 104 + kt * 32 + quad * 8);
        short8 a1 = *(const short8*)(sT + (size_t)(r0 + 16) * 104 + kt * 32 + quad * 8);
        const short8* bp = (const short8*)w2f + kt * 6 * 64 + lane;
#pragma unroll
        for (int nt = 0; nt < 6; nt++) {
            short8 b = bp[nt * 64];
            acc2[0][nt] = __builtin_amdgcn_mfma_f32_16x16x32_bf16(a0, b, acc2[0][nt], 0, 0, 0);
            acc2[1][nt] = __builtin_amdgcn_mfma_f32_16x16x32_bf16(a1, b, acc2[1][nt], 0, 0, 0);
        }
    }

    // bias + residual + LayerNorm; write bf16 result back into A's e-columns
#pragma unroll
    for (int mt = 0; mt < 2; mt++) {
#pragma unroll
        for (int r = 0; r < 4; r++) {
            int row = wave * 32 + mt * 16 + quad * 4 + r;
            float ss = 0.f, qq = 0.f;
#pragma unroll
            for (int nt = 0; nt < 6; nt++) {
                int col = nt * 16 + l15;
                float v = acc2[mt][nt][r] + b2v[nt];
                if (col < EDGE_DIM) v += bf2f(sAu[row * 168 + 48 + col]);
                else v = 0.f;
                acc2[mt][nt][r] = v;
                ss += v;
                qq = fmaf(v, v, qq);
            }
            ss += __shfl_xor(ss, 1); ss += __shfl_xor(ss, 2);
            ss += __shfl_xor(ss, 4); ss += __shfl_xor(ss, 8);
            qq += __shfl_xor(qq, 1); qq += __shfl_xor(qq, 2);
            qq += __shfl_xor(qq, 4); qq += __shfl_xor(qq, 8);
            float mean = ss * (1.f / EDGE_DIM);
            float var  = qq * (1.f / EDGE_DIM) - mean * mean;
            float rstd = rsqrtf(var + LN_EPS);
#pragma unroll
            for (int nt = 0; nt < 6; nt++) {
                int col = nt * 16 + l15;
                if (col < EDGE_DIM) {
                    float o = (acc2[mt][nt][r] - mean) * rstd * gv[nt] + bbv[nt];
                    ((ushort*)sA32)[row * 168 + 48 + col] = f2bf(o);
                }
            }
        }
    }
    __syncthreads();

    // cooperative coalesced store of e_new (128 rows x 42 dwords)
    uint* dst32 = (uint*)e_bf + (size_t)e0 * 42;
#pragma unroll
    for (int i = 0; i < 21; i++) {
        int idx = tid + 256 * i;            // < 5376
        int row = idx / 42, d = idx - row * 42;
        dst32[idx] = sA32[row * 84 + 24 + d];
    }
}

// ---------------- phi_v MFMA kernel + scatter-add ----------------
__global__ __launch_bounds__(256, 2)
void k_edge_v(const ushort* __restrict__ h_bf, const ushort* __restrict__ e_bf,
              const int* __restrict__ ei,
              const ushort* __restrict__ v1f, const ushort* __restrict__ v2f,
              const float* __restrict__ vb1, const float* __restrict__ vb2,
              float* __restrict__ agg) {
    __shared__ __align__(16) uint sA32[128 * 84];
    __shared__ __align__(16) ushort sT[128 * 40];
    __shared__ int s_idx[256];

    const int tid = threadIdx.x;
    const int e0 = blockIdx.x * 128;
    s_idx[tid] = ei[(size_t)(tid >> 7) * N_EDGES + e0 + (tid & 127)];
    __syncthreads();

    {
        int e = tid >> 1, hf = tid & 1;
        int src = s_idx[e], dst = s_idx[128 + e];
        const uint* hb = (const uint*)h_bf;
        uint* row = sA32 + e * 84;
#pragma unroll
        for (int i = 0; i < 6; i++) row[hf * 6 + i] = hb[src * 12 + hf * 6 + i];
#pragma unroll
        for (int i = 0; i < 6; i++) row[12 + hf * 6 + i] = hb[dst * 12 + hf * 6 + i];
        const uint* er = (const uint*)e_bf + (size_t)(e0 + e) * 42;
#pragma unroll
        for (int i = 0; i < 21; i++) { int jd = hf * 21 + i; row[24 + jd] = er[jd]; }
#pragma unroll
        for (int i = 0; i < 7; i++) row[66 + hf * 7 + i] = 0u;
    }

    const int lane = tid & 63, wave = tid >> 6;
    const int quad = lane >> 4, l15 = lane & 15;
    float vb1v[2], vb2v[2];
#pragma unroll
    for (int nt = 0; nt < 2; nt++) {
        int col = nt * 16 + l15;
        bool ok = col < HIDDEN;
        vb1v[nt] = ok ? vb1[col] : 0.f;
        vb2v[nt] = ok ? vb2[col] : 0.f;
    }
    __syncthreads();

    const ushort* sAu = (const ushort*)sA32;
    const int r0 = wave * 32 + l15;

    f32x4 acc[2][2];
#pragma unroll
    for (int mt = 0; mt < 2; mt++)
#pragma unroll
        for (int nt = 0; nt < 2; nt++) acc[mt][nt] = (f32x4)0.f;

#pragma unroll
    for (int kt = 0; kt < 5; kt++) {
        short8 a0 = *(const short8*)(sAu + (size_t)r0 * 168 + kt * 32 + quad * 8);
        short8 a1 = *(const short8*)(sAu + (size_t)(r0 + 16) * 168 + kt * 32 + quad * 8);
        const short8* bp = (const short8*)v1f + kt * 2 * 64 + lane;
#pragma unroll
        for (int nt = 0; nt < 2; nt++) {
            short8 b = bp[nt * 64];
            acc[0][nt] = __builtin_amdgcn_mfma_f32_16x16x32_bf16(a0, b, acc[0][nt], 0, 0, 0);
            acc[1][nt] = __builtin_amdgcn_mfma_f32_16x16x32_bf16(a1, b, acc[1][nt], 0, 0, 0);
        }
    }

#pragma unroll
    for (int mt = 0; mt < 2; mt++)
#pragma unroll
        for (int nt = 0; nt < 2; nt++)
#pragma unroll
            for (int r = 0; r < 4; r++) {
                int row = wave * 32 + mt * 16 + quad * 4 + r;
                sT[row * 40 + nt * 16 + l15] = f2bf(gelu_exact(acc[mt][nt][r] + vb1v[nt]));
            }
    __syncthreads();

    f32x4 acc2[2][2];
#pragma unroll
    for (int mt = 0; mt < 2; mt++)
#pragma unroll
        for (int nt = 0; nt < 2; nt++) acc2[mt][nt] = (f32x4)0.f;
    {
        short8 a0 = *(const short8*)(sT + (size_t)r0 * 40 + quad * 8);
        short8 a1 = *(const short8*)(sT + (size_t)(r0 + 16) * 40 + quad * 8);
        const short8* bp = (const short8*)v2f + lane;
#pragma unroll
        for (int nt = 0; nt < 2; nt++) {
            short8 b = bp[nt * 64];
            acc2[0][nt] = __builtin_amdgcn_mfma_f32_16x16x32_bf16(a0, b, acc2[0][nt], 0, 0, 0);
            acc2[1][nt] = __builtin_amdgcn_mfma_f32_16x16x32_bf16(a1, b, acc2[1][nt], 0, 0, 0);
        }
    }

#pragma unroll
    for (int mt = 0; mt < 2; mt++)
#pragma unroll
        for (int nt = 0; nt < 2; nt++) {
            int col = nt * 16 + l15;
            if (col < HIDDEN) {
#pragma unroll
                for (int r = 0; r < 4; r++) {
                    int row = wave * 32 + mt * 16 + quad * 4 + r;
                    int dst = s_idx[128 + row];
                    atomicAdd(&agg[(size_t)dst * HIDDEN + col], acc2[mt][nt][r] + vb2v[nt]);
                }
            }
        }
}

// ---------------- node update: h = LN(h + agg/counts) ----------------
__global__ void k_node_up(float* __restrict__ h, ushort* __restrict__ h_bf,
                          const float* __restrict__ agg,
                          const int* __restrict__ cnt,
                          const float* __restrict__ g, const float* __restrict__ b) {
    int n = blockIdx.x * blockDim.x + threadIdx.x;
    if (n >= N_NODES) return;
    int c = cnt[n]; if (c < 1) c = 1;
    float inv = 1.0f / (float)c;
    float v[HIDDEN];
    float s = 0.f;
#pragma unroll
    for (int j = 0; j < HIDDEN; j++) {
        v[j] = h[(size_t)n * HIDDEN + j] + agg[(size_t)n * HIDDEN + j] * inv;
        s += v[j];
    }
    float mean = s * (1.f / HIDDEN);
    float sq = 0.f;
#pragma unroll
    for (int j = 0; j < HIDDEN; j++) { float d = v[j] - mean; sq = fmaf(d, d, sq); }
    float rstd = rsqrtf(sq * (1.f / HIDDEN) + LN_EPS);
#pragma unroll
    for (int j = 0; j < HIDDEN; j++) {
        float o = (v[j] - mean) * rstd * g[j] + b[j];
        h[(size_t)n * HIDDEN + j] = o;
        h_bf[(size_t)n * HIDDEN + j] = f2bf(o);
    }
}

// ---------------- final: out = mu + intrinsic + context(h) ----------------
__global__ void k_final(const float* __restrict__ h, const float* __restrict__ intr,
                        const float* __restrict__ ch_w1, const float* __restrict__ ch_b1,
                        const float* __restrict__ ch_w2, const float* __restrict__ ch_b2,
                        const float* __restrict__ mu, float* __restrict__ out) {
    int n = blockIdx.x * blockDim.x + threadIdx.x;
    if (n >= N_NODES) return;
    float hv[HIDDEN];
#pragma unroll
    for (int j = 0; j < HIDDEN; j++) hv[j] = h[(size_t)n * HIDDEN + j];
    float acc = ch_b2[0];
    for (int j = 0; j < HEAD_HIDDEN; j++) {
        float t = ch_b1[j];
#pragma unroll
        for (int k = 0; k < HIDDEN; k++) t = fmaf(hv[k], ch_w1[k * HEAD_HIDDEN + j], t);
        acc = fmaf(gelu_exact(t), ch_w2[j], acc);
    }
    out[n] = mu[0] + intr[n] + acc;
}

extern "C" void kernel_launch(void* const* d_in, const int* in_sizes, int n_in,
                              void* d_out, int out_size, void* d_ws, size_t ws_size,
                              hipStream_t stream) {
    const float* x        = (const float*)d_in[0];
    const float* edge_attr= (const float*)d_in[1];
    const float* node_w   = (const float*)d_in[2];
    const float* node_b   = (const float*)d_in[3];
    const float* ih_w1    = (const float*)d_in[4];
    const float* ih_b1    = (const float*)d_in[5];
    const float* ih_w2    = (const float*)d_in[6];
    const float* ih_b2    = (const float*)d_in[7];
    const float* pe_w1    = (const float*)d_in[8];
    const float* pe_b1    = (const float*)d_in[9];
    const float* pe_w2    = (const float*)d_in[10];
    const float* pe_b2    = (const float*)d_in[11];
    const float* pv_w1    = (const float*)d_in[12];
    const float* pv_b1    = (const float*)d_in[13];
    const float* pv_w2    = (const float*)d_in[14];
    const float* pv_b2    = (const float*)d_in[15];
    const float* ne_g     = (const float*)d_in[16];
    const float* ne_b     = (const float*)d_in[17];
    const float* nv_g     = (const float*)d_in[18];
    const float* nv_b     = (const float*)d_in[19];
    const float* ch_w1    = (const float*)d_in[20];
    const float* ch_b1    = (const float*)d_in[21];
    const float* ch_w2    = (const float*)d_in[22];
    const float* ch_b2    = (const float*)d_in[23];
    const float* mu       = (const float*)d_in[24];
    const int*   ei       = (const int*)d_in[25];

    char* ws = (char*)d_ws;
    float*  h    = (float*)ws;  ws += (size_t)N_NODES * HIDDEN * 4;
    float*  agg  = (float*)ws;  ws += (size_t)N_NODES * HIDDEN * 4;
    float*  intr = (float*)ws;  ws += (size_t)N_NODES * 4;
    int*    cnt  = (int*)ws;    ws += (size_t)N_NODES * 4;
    ushort* h_bf = (ushort*)ws; ws += (size_t)N_NODES * HIDDEN * 2;
    ushort* wp   = (ushort*)ws; ws += (size_t)61440 * 2;
    ws = (char*)(((size_t)ws + 255) & ~(size_t)255);
    ushort* e_bf = (ushort*)ws; ws += (size_t)N_EDGES * EDGE_DIM * 2;

    // packed-weight region offsets (in bf16 elements)
    const ushort* we1[2] = { wp + 0 * 15360, wp + 1 * 15360 };
    const ushort* we2[2] = { wp + 30720 + 0 * 9216, wp + 30720 + 1 * 9216 };
    const ushort* wv1[2] = { wp + 49152 + 0 * 5120, wp + 49152 + 1 * 5120 };
    const ushort* wv2[2] = { wp + 59392 + 0 * 1024, wp + 59392 + 1 * 1024 };

    hipMemsetAsync(cnt, 0, (size_t)N_NODES * 4, stream);
    k_prep_w<<<240, 256, 0, stream>>>(pe_w1, pe_w2, pv_w1, pv_w2, wp);
    k_counts<<<(N_EDGES + 255) / 256, 256, 0, stream>>>(ei, cnt);
    k_node_in<<<(N_NODES + 255) / 256, 256, 0, stream>>>(
        x, node_w, node_b, ih_w1, ih_b1, ih_w2, ih_b2, h, h_bf, intr);

    const int eb = N_EDGES / 128;   // 6250, exact
    for (int L = 0; L < 2; L++) {
        k_edge_e<<<eb, 256, 0, stream>>>(
            h_bf, (L == 0) ? edge_attr : (const float*)nullptr, e_bf, ei,
            we1[L], we2[L],
            pe_b1 + (size_t)L * EDGE_DIM, pe_b2 + (size_t)L * EDGE_DIM,
            ne_g + (size_t)L * EDGE_DIM, ne_b + (size_t)L * EDGE_DIM);
        hipMemsetAsync(agg, 0, (size_t)N_NODES * HIDDEN * 4, stream);
        k_edge_v<<<eb, 256, 0, stream>>>(
            h_bf, e_bf, ei, wv1[L], wv2[L],
            pv_b1 + (size_t)L * HIDDEN, pv_b2 + (size_t)L * HIDDEN, agg);
        k_node_up<<<(N_NODES + 255) / 256, 256, 0, stream>>>(
            h, h_bf, agg, cnt, nv_g + (size_t)L * HIDDEN, nv_b + (size_t)L * HIDDEN);
    }
    k_final<<<(N_NODES + 255) / 256, 256, 0, stream>>>(
        h, intr, ch_w1, ch_b1, ch_w2, ch_b2, mu, (float*)d_out);
}

// Round 4
// 1013.622 us; speedup vs baseline: 5.0497x; 1.1436x over previous
//
#include <hip/hip_runtime.h>
#include <math.h>

#define N_NODES 100000
#define N_EDGES 800000
#define NODE_IN 32
#define EDGE_DIM 84
#define HIDDEN 24
#define HEAD_HIDDEN 20
#define CAT_DIM 132
#define LN_EPS 1e-5f

typedef __attribute__((ext_vector_type(8))) short short8;
typedef __attribute__((ext_vector_type(4))) float f32x4;
typedef unsigned int uint;
typedef unsigned short ushort;

__device__ __forceinline__ float gelu_exact(float x) {
    return 0.5f * x * (1.0f + erff(x * 0.70710678118654752f));
}
__device__ __forceinline__ ushort f2bf(float f) {
    union { float f; uint u; } c; c.f = f;
    uint u = c.u;
    return (ushort)((u + 0x7fffu + ((u >> 16) & 1u)) >> 16);
}
__device__ __forceinline__ float bf2f(ushort s) {
    union { uint u; float f; } c; c.u = ((uint)s) << 16; return c.f;
}

// ---------------- weight pre-pack to MFMA-fragment-major bf16 ----------------
// frag element (lane, j) = W[kt*32 + (lane>>4)*8 + j][nt*16 + (lane&15)], zero-padded.
// regions (frags of 512 bf16): pe_w1 2L*30 | pe_w2 2L*18 | pv_w1 2L*10 | pv_w2 2L*2
__global__ void k_prep_w(const float* __restrict__ pe_w1, const float* __restrict__ pe_w2,
                         const float* __restrict__ pv_w1, const float* __restrict__ pv_w2,
                         ushort* __restrict__ wp) {
    int idx = blockIdx.x * 256 + threadIdx.x;        // < 61440
    int j = idx & 7;
    int lane = (idx >> 3) & 63;
    int frag = idx >> 9;                             // 0..119
    int kq = (lane >> 4) * 8 + j;
    int n15 = lane & 15;
    float v = 0.f;
    if (frag < 60) {                                 // pe_w1: [L][5kt][6nt]
        int l = frag / 30, f = frag % 30;
        int kt = f / 6, nt = f % 6;
        int k = kt * 32 + kq, n = nt * 16 + n15;
        if (k < CAT_DIM && n < EDGE_DIM) v = pe_w1[(l * CAT_DIM + k) * EDGE_DIM + n];
    } else if (frag < 96) {                          // pe_w2: [L][3kt][6nt]
        int f2 = frag - 60; int l = f2 / 18, f = f2 % 18;
        int kt = f / 6, nt = f % 6;
        int k = kt * 32 + kq, n = nt * 16 + n15;
        if (k < EDGE_DIM && n < EDGE_DIM) v = pe_w2[(l * EDGE_DIM + k) * EDGE_DIM + n];
    } else if (frag < 116) {                         // pv_w1: [L][5kt][2nt]
        int f2 = frag - 96; int l = f2 / 10, f = f2 % 10;
        int kt = f / 2, nt = f % 2;
        int k = kt * 32 + kq, n = nt * 16 + n15;
        if (k < CAT_DIM && n < HIDDEN) v = pv_w1[(l * CAT_DIM + k) * HIDDEN + n];
    } else {                                         // pv_w2: [L][1kt][2nt]
        int f2 = frag - 116; int l = f2 / 2, nt = f2 % 2;
        int k = kq, n = nt * 16 + n15;
        if (k < HIDDEN && n < HIDDEN) v = pv_w2[(l * HIDDEN + k) * HIDDEN + n];
    }
    wp[idx] = f2bf(v);
}

// ---------------- node input projection + intrinsic head ----------------
__global__ void k_node_in(const float* __restrict__ x,
                          const float* __restrict__ node_w, const float* __restrict__ node_b,
                          const float* __restrict__ ih_w1, const float* __restrict__ ih_b1,
                          const float* __restrict__ ih_w2, const float* __restrict__ ih_b2,
                          float* __restrict__ h, ushort* __restrict__ h_bf,
                          float* __restrict__ intr) {
    int n = blockIdx.x * blockDim.x + threadIdx.x;
    if (n >= N_NODES) return;
    float xv[NODE_IN];
    const float4* xp = (const float4*)(x + (size_t)n * NODE_IN);
#pragma unroll
    for (int i = 0; i < NODE_IN / 4; i++) {
        float4 v = xp[i];
        xv[4*i+0] = v.x; xv[4*i+1] = v.y; xv[4*i+2] = v.z; xv[4*i+3] = v.w;
    }
    float hv[HIDDEN];
#pragma unroll
    for (int j = 0; j < HIDDEN; j++) hv[j] = node_b[j];
    for (int k = 0; k < NODE_IN; k++) {
        float xk = xv[k];
#pragma unroll
        for (int j = 0; j < HIDDEN; j++) hv[j] = fmaf(xk, node_w[k * HIDDEN + j], hv[j]);
    }
#pragma unroll
    for (int j = 0; j < HIDDEN; j++) {
        h[(size_t)n * HIDDEN + j] = hv[j];
        h_bf[(size_t)n * HIDDEN + j] = f2bf(hv[j]);
    }
    float acc = ih_b2[0];
    for (int j = 0; j < HEAD_HIDDEN; j++) {
        float t = ih_b1[j];
#pragma unroll
        for (int k = 0; k < HIDDEN; k++) t = fmaf(hv[k], ih_w1[k * HEAD_HIDDEN + j], t);
        acc = fmaf(gelu_exact(t), ih_w2[j], acc);
    }
    intr[n] = acc;
}

__global__ void k_counts(const int* __restrict__ ei, int* __restrict__ cnt) {
    int e = blockIdx.x * blockDim.x + threadIdx.x;
    if (e >= N_EDGES) return;
    atomicAdd(&cnt[ei[N_EDGES + e]], 1);
}

// A-fragment gather from global: cat layout [src h 0-23 | dst h 24-47 | e 48-143 | pad].
// Chunks beyond real data are clamped to a safe address; zero-padded weights kill them.
__device__ __forceinline__ short8 ld_catA(const ushort* __restrict__ h_bf,
                                          const float* __restrict__ eattr,
                                          const ushort* __restrict__ e_bf,
                                          int src, int dst, long rowg, int c) {
    if (c < 48) {
        const ushort* p = (c < 24) ? h_bf + (size_t)src * 24 + c
                                   : h_bf + (size_t)dst * 24 + (c - 24);
        return *(const short8*)p;
    }
    int ec = c - 48;
    if (eattr) {
        const float* q = eattr + rowg * 84;
        f32x4 lo = *(const f32x4*)(q + ((ec <= 80) ? ec : 0));
        f32x4 hi = *(const f32x4*)(q + ((ec <= 76) ? (ec + 4) : 0));
        short8 r;
        r[0] = (short)f2bf(lo[0]); r[1] = (short)f2bf(lo[1]);
        r[2] = (short)f2bf(lo[2]); r[3] = (short)f2bf(lo[3]);
        r[4] = (short)f2bf(hi[0]); r[5] = (short)f2bf(hi[1]);
        r[6] = (short)f2bf(hi[2]); r[7] = (short)f2bf(hi[3]);
        return r;
    }
    return *(const short8*)(e_bf + rowg * 96 + ((ec < 96) ? ec : 0));
}

// Same gather but e part comes from LDS (e_new), block-local row.
__device__ __forceinline__ short8 ld_catV(const ushort* __restrict__ h_bf,
                                          const ushort* __restrict__ sT,
                                          int src, int dst, int rowL, int c) {
    if (c < 48) {
        const ushort* p = (c < 24) ? h_bf + (size_t)src * 24 + c
                                   : h_bf + (size_t)dst * 24 + (c - 24);
        return *(const short8*)p;
    }
    int ec = c - 48;
    return *(const short8*)(sT + rowL * 104 + ((ec < 96) ? ec : 0));
}

// ---------------- fused per-layer edge kernel: phi_e + LN + phi_v + scatter ----------------
// 128 edges/block, 4 waves, rows wave-private -> 2 barriers total.
__global__ __launch_bounds__(256, 4)
void k_edge_fused(const ushort* __restrict__ h_bf,
                  const float* __restrict__ eattr,   // layer0 edge_attr fp32, else null
                  ushort* __restrict__ e_bf,         // padded 96-col bf16; in (L>0) / out
                  const int* __restrict__ ei,
                  const ushort* __restrict__ w1f, const ushort* __restrict__ w2f,
                  const ushort* __restrict__ v1f, const ushort* __restrict__ v2f,
                  const float* __restrict__ b1, const float* __restrict__ b2,
                  const float* __restrict__ g, const float* __restrict__ bb,
                  const float* __restrict__ vb1, const float* __restrict__ vb2,
                  float* __restrict__ agg, int store_e) {
    __shared__ __align__(16) ushort sT[128 * 104];   // t1 then e_new, pitch 104
    __shared__ __align__(16) ushort sTV[128 * 40];   // t_v, pitch 40
    __shared__ int s_idx[256];

    const int tid = threadIdx.x;
    const int e0 = blockIdx.x * 128;
    s_idx[tid] = ei[(size_t)(tid >> 7) * N_EDGES + e0 + (tid & 127)];
    __syncthreads();

    const int lane = tid & 63, wave = tid >> 6;
    const int quad = lane >> 4, l15 = lane & 15;
    const int cbase = quad * 8;
    const int rA0 = wave * 32 + l15;                 // A-frag rows rA0, rA0+16
    int srcA[2], dstA[2];
    srcA[0] = s_idx[rA0];      dstA[0] = s_idx[128 + rA0];
    srcA[1] = s_idx[rA0 + 16]; dstA[1] = s_idx[128 + rA0 + 16];

    // ---- GEMM1: t1 = cat @ w1 ----
    f32x4 acc[2][6];
#pragma unroll
    for (int mt = 0; mt < 2; mt++)
#pragma unroll
        for (int nt = 0; nt < 6; nt++) acc[mt][nt] = (f32x4)0.f;
#pragma unroll
    for (int kt = 0; kt < 5; kt++) {
        int c = kt * 32 + cbase;
        short8 a0 = ld_catA(h_bf, eattr, e_bf, srcA[0], dstA[0], (long)(e0 + rA0), c);
        short8 a1 = ld_catA(h_bf, eattr, e_bf, srcA[1], dstA[1], (long)(e0 + rA0 + 16), c);
        const short8* bp = (const short8*)w1f + kt * 6 * 64 + lane;
#pragma unroll
        for (int nt = 0; nt < 6; nt++) {
            short8 b = bp[nt * 64];
            acc[0][nt] = __builtin_amdgcn_mfma_f32_16x16x32_bf16(a0, b, acc[0][nt], 0, 0, 0);
            acc[1][nt] = __builtin_amdgcn_mfma_f32_16x16x32_bf16(a1, b, acc[1][nt], 0, 0, 0);
        }
    }
    // gelu -> sT (wave-private rows; pad cols come out exactly 0)
#pragma unroll
    for (int nt = 0; nt < 6; nt++) {
        int col = nt * 16 + l15;
        float bv = (col < EDGE_DIM) ? b1[col] : 0.f;
#pragma unroll
        for (int mt = 0; mt < 2; mt++)
#pragma unroll
            for (int r = 0; r < 4; r++) {
                int row = wave * 32 + mt * 16 + quad * 4 + r;
                sT[row * 104 + col] = f2bf(gelu_exact(acc[mt][nt][r] + bv));
            }
    }

    // ---- GEMM2: t1 @ w2 (rows wave-private, no barrier) ----
    f32x4 acc2[2][6];
#pragma unroll
    for (int mt = 0; mt < 2; mt++)
#pragma unroll
        for (int nt = 0; nt < 6; nt++) acc2[mt][nt] = (f32x4)0.f;
#pragma unroll
    for (int kt = 0; kt < 3; kt++) {
        short8 a0 = *(const short8*)(sT + (size_t)rA0 * 104 + kt * 32 + cbase);
        short8 a1 = *(const short8*)(sT + (size_t)(rA0 + 16) * 104 + kt * 32 + cbase);
        const short8* bp = (const short8*)w2f + kt * 6 * 64 + lane;
#pragma unroll
        for (int nt = 0; nt < 6; nt++) {
            short8 b = bp[nt * 64];
            acc2[0][nt] = __builtin_amdgcn_mfma_f32_16x16x32_bf16(a0, b, acc2[0][nt], 0, 0, 0);
            acc2[1][nt] = __builtin_amdgcn_mfma_f32_16x16x32_bf16(a1, b, acc2[1][nt], 0, 0, 0);
        }
    }

    // ---- bias + residual + LayerNorm -> e_new (bf16) back into sT ----
#pragma unroll
    for (int mt = 0; mt < 2; mt++) {
#pragma unroll
        for (int r = 0; r < 4; r++) {
            int row = wave * 32 + mt * 16 + quad * 4 + r;
            long rg = e0 + row;
            float vv[6];
            float ss = 0.f, qq = 0.f;
#pragma unroll
            for (int nt = 0; nt < 6; nt++) {
                int col = nt * 16 + l15;
                float v = 0.f;
                if (col < EDGE_DIM) {
                    v = acc2[mt][nt][r] + b2[col];
                    v += eattr ? eattr[rg * 84 + col] : bf2f(e_bf[rg * 96 + col]);
                }
                vv[nt] = v; ss += v; qq = fmaf(v, v, qq);
            }
            ss += __shfl_xor(ss, 1); ss += __shfl_xor(ss, 2);
            ss += __shfl_xor(ss, 4); ss += __shfl_xor(ss, 8);
            qq += __shfl_xor(qq, 1); qq += __shfl_xor(qq, 2);
            qq += __shfl_xor(qq, 4); qq += __shfl_xor(qq, 8);
            float mean = ss * (1.f / EDGE_DIM);
            float var  = qq * (1.f / EDGE_DIM) - mean * mean;
            float rstd = rsqrtf(var + LN_EPS);
#pragma unroll
            for (int nt = 0; nt < 6; nt++) {
                int col = nt * 16 + l15;
                if (col < EDGE_DIM)
                    sT[row * 104 + col] = f2bf((vv[nt] - mean) * rstd * g[col] + bb[col]);
            }
        }
    }

    // ---- GEMM_V1: [h_src|h_dst|e_new] @ v1 (e from sT, wave-private rows) ----
    f32x4 av[2][2];
#pragma unroll
    for (int mt = 0; mt < 2; mt++)
#pragma unroll
        for (int nt = 0; nt < 2; nt++) av[mt][nt] = (f32x4)0.f;
#pragma unroll
    for (int kt = 0; kt < 5; kt++) {
        int c = kt * 32 + cbase;
        short8 a0 = ld_catV(h_bf, sT, srcA[0], dstA[0], rA0, c);
        short8 a1 = ld_catV(h_bf, sT, srcA[1], dstA[1], rA0 + 16, c);
        const short8* bp = (const short8*)v1f + kt * 2 * 64 + lane;
#pragma unroll
        for (int nt = 0; nt < 2; nt++) {
            short8 b = bp[nt * 64];
            av[0][nt] = __builtin_amdgcn_mfma_f32_16x16x32_bf16(a0, b, av[0][nt], 0, 0, 0);
            av[1][nt] = __builtin_amdgcn_mfma_f32_16x16x32_bf16(a1, b, av[1][nt], 0, 0, 0);
        }
    }
    // gelu -> sTV
#pragma unroll
    for (int nt = 0; nt < 2; nt++) {
        int col = nt * 16 + l15;
        float bv = (col < HIDDEN) ? vb1[col] : 0.f;
#pragma unroll
        for (int mt = 0; mt < 2; mt++)
#pragma unroll
            for (int r = 0; r < 4; r++) {
                int row = wave * 32 + mt * 16 + quad * 4 + r;
                sTV[row * 40 + col] = f2bf(gelu_exact(av[mt][nt][r] + bv));
            }
    }

    // ---- GEMM_V2: t_v @ v2 ----
    f32x4 av2[2][2];
#pragma unroll
    for (int mt = 0; mt < 2; mt++)
#pragma unroll
        for (int nt = 0; nt < 2; nt++) av2[mt][nt] = (f32x4)0.f;
    {
        short8 a0 = *(const short8*)(sTV + (size_t)rA0 * 40 + cbase);
        short8 a1 = *(const short8*)(sTV + (size_t)(rA0 + 16) * 40 + cbase);
        const short8* bp = (const short8*)v2f + lane;
#pragma unroll
        for (int nt = 0; nt < 2; nt++) {
            short8 b = bp[nt * 64];
            av2[0][nt] = __builtin_amdgcn_mfma_f32_16x16x32_bf16(a0, b, av2[0][nt], 0, 0, 0);
            av2[1][nt] = __builtin_amdgcn_mfma_f32_16x16x32_bf16(a1, b, av2[1][nt], 0, 0, 0);
        }
    }
    // scatter-add m into agg
#pragma unroll
    for (int nt = 0; nt < 2; nt++) {
        int col = nt * 16 + l15;
        if (col < HIDDEN) {
            float bv = vb2[col];
#pragma unroll
            for (int mt = 0; mt < 2; mt++)
#pragma unroll
                for (int r = 0; r < 4; r++) {
                    int row = wave * 32 + mt * 16 + quad * 4 + r;
                    int d = s_idx[128 + row];
                    atomicAdd(&agg[(size_t)d * HIDDEN + col], av2[mt][nt][r] + bv);
                }
        }
    }

    // ---- store e_new (padded 96-col bf16), skipped on last layer ----
    if (store_e) {
        __syncthreads();
        const uint* sTu = (const uint*)sT;           // pitch 52 dwords
        uint* dst32 = (uint*)e_bf + (size_t)e0 * 48;
#pragma unroll
        for (int i = 0; i < 24; i++) {
            int idx = tid + 256 * i;                 // < 6144
            int row = idx / 48, d = idx - row * 48;
            dst32[idx] = sTu[row * 52 + d];
        }
    }
}

// ---------------- node update: h = LN(h + agg/counts) ----------------
__global__ void k_node_up(float* __restrict__ h, ushort* __restrict__ h_bf,
                          const float* __restrict__ agg,
                          const int* __restrict__ cnt,
                          const float* __restrict__ g, const float* __restrict__ b) {
    int n = blockIdx.x * blockDim.x + threadIdx.x;
    if (n >= N_NODES) return;
    int c = cnt[n]; if (c < 1) c = 1;
    float inv = 1.0f / (float)c;
    float v[HIDDEN];
    float s = 0.f;
#pragma unroll
    for (int j = 0; j < HIDDEN; j++) {
        v[j] = h[(size_t)n * HIDDEN + j] + agg[(size_t)n * HIDDEN + j] * inv;
        s += v[j];
    }
    float mean = s * (1.f / HIDDEN);
    float sq = 0.f;
#pragma unroll
    for (int j = 0; j < HIDDEN; j++) { float d = v[j] - mean; sq = fmaf(d, d, sq); }
    float rstd = rsqrtf(sq * (1.f / HIDDEN) + LN_EPS);
#pragma unroll
    for (int j = 0; j < HIDDEN; j++) {
        float o = (v[j] - mean) * rstd * g[j] + b[j];
        h[(size_t)n * HIDDEN + j] = o;
        h_bf[(size_t)n * HIDDEN + j] = f2bf(o);
    }
}

// ---------------- final: out = mu + intrinsic + context(h) ----------------
__global__ void k_final(const float* __restrict__ h, const float* __restrict__ intr,
                        const float* __restrict__ ch_w1, const float* __restrict__ ch_b1,
                        const float* __restrict__ ch_w2, const float* __restrict__ ch_b2,
                        const float* __restrict__ mu, float* __restrict__ out) {
    int n = blockIdx.x * blockDim.x + threadIdx.x;
    if (n >= N_NODES) return;
    float hv[HIDDEN];
#pragma unroll
    for (int j = 0; j < HIDDEN; j++) hv[j] = h[(size_t)n * HIDDEN + j];
    float acc = ch_b2[0];
    for (int j = 0; j < HEAD_HIDDEN; j++) {
        float t = ch_b1[j];
#pragma unroll
        for (int k = 0; k < HIDDEN; k++) t = fmaf(hv[k], ch_w1[k * HEAD_HIDDEN + j], t);
        acc = fmaf(gelu_exact(t), ch_w2[j], acc);
    }
    out[n] = mu[0] + intr[n] + acc;
}

extern "C" void kernel_launch(void* const* d_in, const int* in_sizes, int n_in,
                              void* d_out, int out_size, void* d_ws, size_t ws_size,
                              hipStream_t stream) {
    const float* x        = (const float*)d_in[0];
    const float* edge_attr= (const float*)d_in[1];
    const float* node_w   = (const float*)d_in[2];
    const float* node_b   = (const float*)d_in[3];
    const float* ih_w1    = (const float*)d_in[4];
    const float* ih_b1    = (const float*)d_in[5];
    const float* ih_w2    = (const float*)d_in[6];
    const float* ih_b2    = (const float*)d_in[7];
    const float* pe_w1    = (const float*)d_in[8];
    const float* pe_b1    = (const float*)d_in[9];
    const float* pe_w2    = (const float*)d_in[10];
    const float* pe_b2    = (const float*)d_in[11];
    const float* pv_w1    = (const float*)d_in[12];
    const float* pv_b1    = (const float*)d_in[13];
    const float* pv_w2    = (const float*)d_in[14];
    const float* pv_b2    = (const float*)d_in[15];
    const float* ne_g     = (const float*)d_in[16];
    const float* ne_b     = (const float*)d_in[17];
    const float* nv_g     = (const float*)d_in[18];
    const float* nv_b     = (const float*)d_in[19];
    const float* ch_w1    = (const float*)d_in[20];
    const float* ch_b1    = (const float*)d_in[21];
    const float* ch_w2    = (const float*)d_in[22];
    const float* ch_b2    = (const float*)d_in[23];
    const float* mu       = (const float*)d_in[24];
    const int*   ei       = (const int*)d_in[25];

    char* ws = (char*)d_ws;
    float*  h    = (float*)ws;  ws += (size_t)N_NODES * HIDDEN * 4;
    float*  agg  = (float*)ws;  ws += (size_t)N_NODES * HIDDEN * 4;
    float*  intr = (float*)ws;  ws += (size_t)N_NODES * 4;
    int*    cnt  = (int*)ws;    ws += (size_t)N_NODES * 4;
    ushort* h_bf = (ushort*)ws; ws += (size_t)N_NODES * HIDDEN * 2;
    ushort* wp   = (ushort*)ws; ws += (size_t)61440 * 2;
    ws = (char*)(((size_t)ws + 255) & ~(size_t)255);
    ushort* e_bf = (ushort*)ws; ws += (size_t)N_EDGES * 96 * 2;   // padded 96 cols

    const ushort* we1[2] = { wp + 0 * 15360, wp + 1 * 15360 };
    const ushort* we2[2] = { wp + 30720 + 0 * 9216, wp + 30720 + 1 * 9216 };
    const ushort* wv1[2] = { wp + 49152 + 0 * 5120, wp + 49152 + 1 * 5120 };
    const ushort* wv2[2] = { wp + 59392 + 0 * 1024, wp + 59392 + 1 * 1024 };

    hipMemsetAsync(cnt, 0, (size_t)N_NODES * 4, stream);
    k_prep_w<<<240, 256, 0, stream>>>(pe_w1, pe_w2, pv_w1, pv_w2, wp);
    k_counts<<<(N_EDGES + 255) / 256, 256, 0, stream>>>(ei, cnt);
    k_node_in<<<(N_NODES + 255) / 256, 256, 0, stream>>>(
        x, node_w, node_b, ih_w1, ih_b1, ih_w2, ih_b2, h, h_bf, intr);

    const int eb = N_EDGES / 128;   // 6250, exact
    for (int L = 0; L < 2; L++) {
        hipMemsetAsync(agg, 0, (size_t)N_NODES * HIDDEN * 4, stream);
        k_edge_fused<<<eb, 256, 0, stream>>>(
            h_bf, (L == 0) ? edge_attr : (const float*)nullptr, e_bf, ei,
            we1[L], we2[L], wv1[L], wv2[L],
            pe_b1 + (size_t)L * EDGE_DIM, pe_b2 + (size_t)L * EDGE_DIM,
            ne_g + (size_t)L * EDGE_DIM, ne_b + (size_t)L * EDGE_DIM,
            pv_b1 + (size_t)L * HIDDEN, pv_b2 + (size_t)L * HIDDEN,
            agg, (L == 0) ? 1 : 0);
        k_node_up<<<(N_NODES + 255) / 256, 256, 0, stream>>>(
            h, h_bf, agg, cnt, nv_g + (size_t)L * HIDDEN, nv_b + (size_t)L * HIDDEN);
    }
    k_final<<<(N_NODES + 255) / 256, 256, 0, stream>>>(
        h, intr, ch_w1, ch_b1, ch_w2, ch_b2, mu, (float*)d_out);
}